// Round 10
// baseline (1339.379 us; speedup 1.0000x reference)
//
#include <hip/hip_runtime.h>
#include <math.h>

// Problem constants: B=8, Cin=64, Cout=128, H=W=128, KS=3, N=9, K=576
#define KDIM 576
#define ASTRIDE 584   // ushorts per position row in LDS (576 + 8 pad), 1168 B (8B-aligned)

__device__ inline unsigned short f2bf(float f) {
    unsigned int u = __builtin_bit_cast(unsigned int, f);
    u = u + 0x7FFFu + ((u >> 16) & 1u);          // round-to-nearest-even
    return (unsigned short)(u >> 16);
}

// ---------------- zero-fill x_t (border padding) ----------------
__global__ void k_zero(float4* __restrict__ p, int n4) {
    int i = blockIdx.x * 256 + threadIdx.x;
    if (i < n4) p[i] = make_float4(0.f, 0.f, 0.f, 0.f);
}

// ---------------- pad + NCHW->NHWC transpose ----------------
__global__ __launch_bounds__(256) void k_pad_transpose(
    const float* __restrict__ x, float* __restrict__ x_t) {
    __shared__ float lds[128 * 65];
    int b = blockIdx.x >> 7;
    int h = blockIdx.x & 127;
    for (int e = threadIdx.x; e < 64 * 128; e += 256) {
        int ci = e >> 7, w = e & 127;
        lds[w * 65 + ci] = x[((b * 64 + ci) * 128 + h) * 128 + w];
    }
    __syncthreads();
    for (int e = threadIdx.x; e < 128 * 64; e += 256) {
        int w = e >> 6, ci = e & 63;
        x_t[((b * 130 + h + 1) * 130 + (w + 1)) * 64 + ci] = lds[w * 65 + ci];
    }
}

// ---------------- W_conv -> fp32 co-major, K permuted (k' = n*64+ci) ----------------
// Wcom[co][k'] = Wc[co][ci*9+n]  where k' = n*64+ci
__global__ void k_wct(const float* __restrict__ Wc, float* __restrict__ Wcom) {
    int e = blockIdx.x * 256 + threadIdx.x;
    if (e >= 128 * KDIM) return;
    int kp = e % KDIM, co = e / KDIM;
    int n = kp >> 6, ci = kp & 63;
    Wcom[e] = Wc[co * KDIM + ci * 9 + n];
}

// ---------------- offset + mask 3x3 convs (fp32, proven) ----------------
__global__ __launch_bounds__(256) void k_offmask(
    const float* __restrict__ x_t, const float* __restrict__ Wp, const float* __restrict__ bp,
    const float* __restrict__ Wm, const float* __restrict__ bm,
    float* __restrict__ offs, float* __restrict__ mask) {
    __shared__ float lds[198 * 65];
    int t = blockIdx.x;
    int wt = t & 1, h = (t >> 1) & 127, b = t >> 8;
    int w0 = wt * 64;
    for (int e = threadIdx.x; e < 198 * 64; e += 256) {
        int chunk = e >> 6, ci = e & 63;
        int row = chunk / 66, col = chunk % 66;
        lds[chunk * 65 + ci] = x_t[((b * 130 + h + row) * 130 + (w0 + col)) * 64 + ci];
    }
    __syncthreads();
    for (int e = threadIdx.x; e < 27 * 64; e += 256) {
        int oc = e >> 6, wl = e & 63;
        const float* wrow = (oc < 18) ? (Wp + oc * KDIM) : (Wm + (oc - 18) * KDIM);
        float acc = 0.f;
        for (int ci = 0; ci < 64; ++ci) {
            #pragma unroll
            for (int kx = 0; kx < 3; ++kx) {
                float x0 = lds[(kx * 66 + wl + 0) * 65 + ci];
                float x1 = lds[(kx * 66 + wl + 1) * 65 + ci];
                float x2 = lds[(kx * 66 + wl + 2) * 65 + ci];
                const float* wk = wrow + ci * 9 + kx * 3;
                acc += x0 * wk[0] + x1 * wk[1] + x2 * wk[2];
            }
        }
        int idx = ((b * 128 + h) * 128 + (w0 + wl));
        if (oc < 18) {
            offs[idx * 18 + oc] = acc + bp[oc];
        } else {
            float v = acc + bm[oc - 18];
            mask[idx * 9 + (oc - 18)] = 1.f / (1.f + __expf(-v));
        }
    }
}

// ---------------- main: deformable sample -> register-blocked VALU dot ----------------
// Phases 1-2 identical to R4/R7 (proven). Phase 3: pure fp32 VALU dot
// (the computation class that passed end-to-end in R1/R4/R7), 4co x 4pos per thread.
__global__ __launch_bounds__(256) void k_main(
    const float* __restrict__ x_t, const float* __restrict__ offs,
    const float* __restrict__ mask, const float* __restrict__ Wcom,
    float* __restrict__ out) {
    __shared__ __align__(16) unsigned short a_lds[32 * ASTRIDE];   // 37376 B
    __shared__ int4   pi[288];
    __shared__ float4 pg4[288];

    int blk = blockIdx.x;
    int b  = blk & 7;                  // XCD swizzle: one batch per XCD
    int rem = blk >> 3;
    int h  = rem >> 2;
    int w0 = (rem & 3) * 32;
    int tid = threadIdx.x;

    // phase 1: sampling coords for 32 pos x 9 pts (proven)
    for (int e = tid; e < 288; e += 256) {
        int pos = e / 9, n = e - pos * 9;
        int w = w0 + pos;
        int idx = ((b * 128 + h) * 128 + w);
        float ox = offs[idx * 18 + n];
        float oy = offs[idx * 18 + 9 + n];
        float mv = mask[idx * 9 + n];
        float px = ox + (float)(h + n / 3);
        float py = oy + (float)(w + n % 3);
        float flx = floorf(px), fly = floorf(py);
        float qltx = fminf(fmaxf(flx, 0.f), 129.f);
        float qlty = fminf(fmaxf(fly, 0.f), 129.f);
        float qrbx = fminf(fmaxf(flx + 1.f, 0.f), 129.f);
        float qrby = fminf(fmaxf(fly + 1.f, 0.f), 129.f);
        float pxc = fminf(fmaxf(px, 0.f), 129.f);
        float pyc = fminf(fmaxf(py, 0.f), 129.f);
        float glt = (1.f + qltx - pxc) * (1.f + qlty - pyc);
        float grb = (1.f - qrbx + pxc) * (1.f - qrby + pyc);
        float glb = (1.f + qltx - pxc) * (1.f - qrby + pyc);
        float grt = (1.f - qrbx + pxc) * (1.f + qlty - pyc);
        int ix_lt = (int)qltx, iy_lt = (int)qlty, ix_rb = (int)qrbx, iy_rb = (int)qrby;
        pi[e] = make_int4((ix_lt * 130 + iy_lt) * 64, (ix_rb * 130 + iy_rb) * 64,
                          (ix_lt * 130 + iy_rb) * 64, (ix_rb * 130 + iy_lt) * 64);
        pg4[e] = make_float4(glt * mv, grb * mv, glb * mv, grt * mv);
    }
    __syncthreads();

    // phase 2: gather+blend, a_lds[pos][k' = n*64 + ci] in bf16 (proven)
    {
        const float* xb = x_t + (size_t)b * 130 * 130 * 64;
        int ci = tid & 63;
        for (int it = 0; it < 72; ++it) {
            int point = (tid >> 6) + it * 4;
            int pos = (point * 456) >> 12;          // point/9, exact for point<288
            int n = point - pos * 9;
            int4 o = pi[point];
            float4 g = pg4[point];
            float v = g.x * xb[o.x + ci] + g.y * xb[o.y + ci] +
                      g.z * xb[o.z + ci] + g.w * xb[o.w + ci];
            a_lds[pos * ASTRIDE + n * 64 + ci] = f2bf(v);
        }
    }
    __syncthreads();

    // phase 3: register-blocked VALU dot. thread = (cg = tid&31, pg = tid>>5)
    // covers cos cg*4..+3, positions pg*4..+3. A reads are wave-broadcast.
    int cg = tid & 31, pg = tid >> 5;
    int cg4 = cg * 4, pg4i = pg * 4;
    const float4* W4 = (const float4*)Wcom;          // [co][144] float4
    float acc[4][4];
    #pragma unroll
    for (int c = 0; c < 4; ++c)
        #pragma unroll
        for (int p = 0; p < 4; ++p) acc[c][p] = 0.f;

    for (int k4 = 0; k4 < 144; ++k4) {
        float4 w0 = W4[(cg4 + 0) * 144 + k4];
        float4 w1 = W4[(cg4 + 1) * 144 + k4];
        float4 w2 = W4[(cg4 + 2) * 144 + k4];
        float4 w3 = W4[(cg4 + 3) * 144 + k4];
        #pragma unroll
        for (int p = 0; p < 4; ++p) {
            uint2 ua = *(const uint2*)&a_lds[(pg4i + p) * ASTRIDE + k4 * 4];
            float a0 = __builtin_bit_cast(float, ua.x << 16);
            float a1 = __builtin_bit_cast(float, ua.x & 0xFFFF0000u);
            float a2 = __builtin_bit_cast(float, ua.y << 16);
            float a3 = __builtin_bit_cast(float, ua.y & 0xFFFF0000u);
            acc[0][p] += a0 * w0.x + a1 * w0.y + a2 * w0.z + a3 * w0.w;
            acc[1][p] += a0 * w1.x + a1 * w1.y + a2 * w1.z + a3 * w1.w;
            acc[2][p] += a0 * w2.x + a1 * w2.y + a2 * w2.z + a3 * w2.w;
            acc[3][p] += a0 * w3.x + a1 * w3.y + a2 * w3.z + a3 * w3.w;
        }
    }
    __syncthreads();   // all a_lds reads done before aliasing overwrite

    // epilogue: stage via LDS (proven path), then coalesced global stores
    float* outst = (float*)a_lds;                    // [128 co][33]
    #pragma unroll
    for (int c = 0; c < 4; ++c)
        #pragma unroll
        for (int p = 0; p < 4; ++p)
            outst[(cg4 + c) * 33 + (pg4i + p)] = acc[c][p];
    __syncthreads();
    for (int e = tid; e < 4096; e += 256) {
        int co = e >> 5, wl = e & 31;
        out[((size_t)(b * 128 + co) * 16384) + h * 128 + w0 + wl] = outst[co * 33 + wl];
    }
}

// ---------------- BN stats: one block per (b, co) ----------------
__global__ __launch_bounds__(256) void k_stats(
    const float* __restrict__ out, float* __restrict__ partial) {
    __shared__ float s1[256], s2[256];
    int blk = blockIdx.x;
    const float4* p = (const float4*)(out + (size_t)blk * 16384);
    float a1 = 0.f, a2 = 0.f;
    for (int i = threadIdx.x; i < 4096; i += 256) {
        float4 v = p[i];
        a1 += v.x + v.y + v.z + v.w;
        a2 += v.x * v.x + v.y * v.y + v.z * v.z + v.w * v.w;
    }
    s1[threadIdx.x] = a1; s2[threadIdx.x] = a2;
    __syncthreads();
    for (int s = 128; s > 0; s >>= 1) {
        if (threadIdx.x < (unsigned)s) {
            s1[threadIdx.x] += s1[threadIdx.x + s];
            s2[threadIdx.x] += s2[threadIdx.x + s];
        }
        __syncthreads();
    }
    if (threadIdx.x == 0) { partial[blk] = s1[0]; partial[1024 + blk] = s2[0]; }
}

__global__ void k_finalize(const float* __restrict__ partial, const float* __restrict__ gamma,
                           const float* __restrict__ beta, float* __restrict__ sb) {
    int c = threadIdx.x;
    if (c < 128) {
        float s1 = 0.f, s2 = 0.f;
        for (int b = 0; b < 8; ++b) {
            s1 += partial[b * 128 + c];
            s2 += partial[1024 + b * 128 + c];
        }
        const float M = 131072.f;
        float mean = s1 / M;
        float var = fmaxf(s2 / M - mean * mean, 0.f);
        float sc = gamma[c] * rsqrtf(var + 1e-5f);
        sb[c] = sc;
        sb[128 + c] = beta[c] - mean * sc;
    }
}

__global__ void k_bnrelu(float* __restrict__ out, const float* __restrict__ sb) {
    int i = blockIdx.x * 256 + threadIdx.x;
    int c = (i >> 12) & 127;
    float4 v = ((float4*)out)[i];
    float sc = sb[c], bi = sb[128 + c];
    v.x = fmaxf(v.x * sc + bi, 0.f);
    v.y = fmaxf(v.y * sc + bi, 0.f);
    v.z = fmaxf(v.z * sc + bi, 0.f);
    v.w = fmaxf(v.w * sc + bi, 0.f);
    ((float4*)out)[i] = v;
}

extern "C" void kernel_launch(void* const* d_in, const int* in_sizes, int n_in,
                              void* d_out, int out_size, void* d_ws, size_t ws_size,
                              hipStream_t stream) {
    const float* x     = (const float*)d_in[0];
    const float* Wp    = (const float*)d_in[1];
    const float* bp    = (const float*)d_in[2];
    const float* Wm    = (const float*)d_in[3];
    const float* bm    = (const float*)d_in[4];
    const float* Wc    = (const float*)d_in[5];
    const float* gamma = (const float*)d_in[6];
    const float* beta  = (const float*)d_in[7];
    float* out = (float*)d_out;
    float* ws  = (float*)d_ws;

    // ws layout (floats) — same footprint as R1 (proven to fit)
    float* x_t     = ws;                         // 8,652,800
    float* Wcom    = x_t + 8652800;              // 73,728 (576*128 fp32, co-major)
    float* offs    = Wcom + 73728;               // 2,359,296
    float* mask    = offs + 2359296;             // 1,179,648
    float* partial = mask + 1179648;             // 2048
    float* sb      = partial + 2048;             // 256

    k_zero<<<8450, 256, 0, stream>>>((float4*)x_t, 2163200);
    k_pad_transpose<<<1024, 256, 0, stream>>>(x, x_t);
    k_wct<<<288, 256, 0, stream>>>(Wc, Wcom);
    k_offmask<<<2048, 256, 0, stream>>>(x_t, Wp, bp, Wm, bm, offs, mask);
    k_main<<<4096, 256, 0, stream>>>(x_t, offs, mask, Wcom, out);
    k_stats<<<1024, 256, 0, stream>>>(out, partial);
    k_finalize<<<1, 128, 0, stream>>>(partial, gamma, beta, sb);
    k_bnrelu<<<16384, 256, 0, stream>>>(out, sb);
}

// Round 11
// 710.932 us; speedup vs baseline: 1.8840x; 1.8840x over previous
//
#include <hip/hip_runtime.h>
#include <math.h>

// Problem constants: B=8, Cin=64, Cout=128, H=W=128, KS=3, N=9, K=576
#define KDIM 576

__device__ inline unsigned short f2bf(float f) {
    unsigned int u = __builtin_bit_cast(unsigned int, f);
    u = u + 0x7FFFu + ((u >> 16) & 1u);
    return (unsigned short)(u >> 16);
}

// ---------------- zero-fill x_t (border padding) ----------------
__global__ void k_zero(float4* __restrict__ p, int n4) {
    int i = blockIdx.x * 256 + threadIdx.x;
    if (i < n4) p[i] = make_float4(0.f, 0.f, 0.f, 0.f);
}

// ---------------- pad + NCHW->NHWC transpose ----------------
__global__ __launch_bounds__(256) void k_pad_transpose(
    const float* __restrict__ x, float* __restrict__ x_t) {
    __shared__ float lds[128 * 65];
    int b = blockIdx.x >> 7;
    int h = blockIdx.x & 127;
    for (int e = threadIdx.x; e < 64 * 128; e += 256) {
        int ci = e >> 7, w = e & 127;
        lds[w * 65 + ci] = x[((b * 64 + ci) * 128 + h) * 128 + w];
    }
    __syncthreads();
    for (int e = threadIdx.x; e < 128 * 64; e += 256) {
        int w = e >> 6, ci = e & 63;
        x_t[((b * 130 + h + 1) * 130 + (w + 1)) * 64 + ci] = lds[w * 65 + ci];
    }
}

// ---------------- W_conv -> fp32 k-major, K permuted: Wkm[k'][co], k' = n*64+ci ----------------
__global__ void k_wct(const float* __restrict__ Wc, float* __restrict__ Wkm) {
    int e = blockIdx.x * 256 + threadIdx.x;
    if (e >= 128 * KDIM) return;
    int co = e & 127, kp = e >> 7;
    int n = kp >> 6, ci = kp & 63;
    Wkm[e] = Wc[co * KDIM + ci * 9 + n];
}

// ---------------- offset + mask 3x3 convs (fp32, proven) ----------------
__global__ __launch_bounds__(256) void k_offmask(
    const float* __restrict__ x_t, const float* __restrict__ Wp, const float* __restrict__ bp,
    const float* __restrict__ Wm, const float* __restrict__ bm,
    float* __restrict__ offs, float* __restrict__ mask) {
    __shared__ float lds[198 * 65];
    int t = blockIdx.x;
    int wt = t & 1, h = (t >> 1) & 127, b = t >> 8;
    int w0 = wt * 64;
    for (int e = threadIdx.x; e < 198 * 64; e += 256) {
        int chunk = e >> 6, ci = e & 63;
        int row = chunk / 66, col = chunk % 66;
        lds[chunk * 65 + ci] = x_t[((b * 130 + h + row) * 130 + (w0 + col)) * 64 + ci];
    }
    __syncthreads();
    for (int e = threadIdx.x; e < 27 * 64; e += 256) {
        int oc = e >> 6, wl = e & 63;
        const float* wrow = (oc < 18) ? (Wp + oc * KDIM) : (Wm + (oc - 18) * KDIM);
        float acc = 0.f;
        for (int ci = 0; ci < 64; ++ci) {
            #pragma unroll
            for (int kx = 0; kx < 3; ++kx) {
                float x0 = lds[(kx * 66 + wl + 0) * 65 + ci];
                float x1 = lds[(kx * 66 + wl + 1) * 65 + ci];
                float x2 = lds[(kx * 66 + wl + 2) * 65 + ci];
                const float* wk = wrow + ci * 9 + kx * 3;
                acc += x0 * wk[0] + x1 * wk[1] + x2 * wk[2];
            }
        }
        int idx = ((b * 128 + h) * 128 + (w0 + wl));
        if (oc < 18) {
            offs[idx * 18 + oc] = acc + bp[oc];
        } else {
            float v = acc + bm[oc - 18];
            mask[idx * 9 + (oc - 18)] = 1.f / (1.f + __expf(-v));
        }
    }
}

// ---------------- main: deformable sample -> register-blocked VALU dot ----------------
// block = 16 positions; grid = 8192, XCD-pinned per batch.
// Dot topology = R1-proven: lane=co (coalesced k-major weight loads), A broadcast from LDS.
// 2 co x 4 pos = 8 outputs/thread.
__global__ __launch_bounds__(256) void k_main(
    const float* __restrict__ x_t, const float* __restrict__ offs,
    const float* __restrict__ mask, const float* __restrict__ Wkm,
    float* __restrict__ out) {
    __shared__ __align__(16) float a_lds[16 * KDIM];   // 36864 B, fp32; reused as outst
    __shared__ int4   pi[144];
    __shared__ float4 pg4[144];

    int blk = blockIdx.x;
    int b  = blk & 7;                  // XCD swizzle: one batch per XCD
    int rem = blk >> 3;
    int h  = rem >> 3;
    int w0 = (rem & 7) * 16;
    int tid = threadIdx.x;

    // phase 1: sampling coords for 16 pos x 9 pts (proven math)
    if (tid < 144) {
        int e = tid;
        int pos = e / 9, n = e - pos * 9;
        int w = w0 + pos;
        int idx = ((b * 128 + h) * 128 + w);
        float ox = offs[idx * 18 + n];
        float oy = offs[idx * 18 + 9 + n];
        float mv = mask[idx * 9 + n];
        float px = ox + (float)(h + n / 3);
        float py = oy + (float)(w + n % 3);
        float flx = floorf(px), fly = floorf(py);
        float qltx = fminf(fmaxf(flx, 0.f), 129.f);
        float qlty = fminf(fmaxf(fly, 0.f), 129.f);
        float qrbx = fminf(fmaxf(flx + 1.f, 0.f), 129.f);
        float qrby = fminf(fmaxf(fly + 1.f, 0.f), 129.f);
        float pxc = fminf(fmaxf(px, 0.f), 129.f);
        float pyc = fminf(fmaxf(py, 0.f), 129.f);
        float glt = (1.f + qltx - pxc) * (1.f + qlty - pyc);
        float grb = (1.f - qrbx + pxc) * (1.f - qrby + pyc);
        float glb = (1.f + qltx - pxc) * (1.f - qrby + pyc);
        float grt = (1.f - qrbx + pxc) * (1.f + qlty - pyc);
        int ix_lt = (int)qltx, iy_lt = (int)qlty, ix_rb = (int)qrbx, iy_rb = (int)qrby;
        pi[e] = make_int4((ix_lt * 130 + iy_lt) * 64, (ix_rb * 130 + iy_rb) * 64,
                          (ix_lt * 130 + iy_rb) * 64, (ix_rb * 130 + iy_lt) * 64);
        pg4[e] = make_float4(glt * mv, grb * mv, glb * mv, grt * mv);
    }
    __syncthreads();

    // phase 2: gather+blend, a_lds[pos][k' = n*64 + ci] in fp32 (proven pattern)
    {
        const float* xb = x_t + (size_t)b * 130 * 130 * 64;
        int ci = tid & 63;
        for (int it = 0; it < 36; ++it) {
            int point = (tid >> 6) + it * 4;
            int pos = (point * 456) >> 12;          // point/9, exact for point<288
            int n = point - pos * 9;
            int4 o = pi[point];
            float4 g = pg4[point];
            float v = g.x * xb[o.x + ci] + g.y * xb[o.y + ci] +
                      g.z * xb[o.z + ci] + g.w * xb[o.w + ci];
            a_lds[pos * KDIM + n * 64 + ci] = v;
        }
    }
    __syncthreads();

    // phase 3: dot. lane = co (coalesced weights), pg = pos-group; 2 co x 4 pos/thread.
    int lane = tid & 63, pg = tid >> 6;
    float acc[2][4] = {{0.f, 0.f, 0.f, 0.f}, {0.f, 0.f, 0.f, 0.f}};
    for (int k4 = 0; k4 < 144; ++k4) {
        int kk = k4 * 4;
        float w00 = Wkm[(kk + 0) * 128 + lane];
        float w01 = Wkm[(kk + 1) * 128 + lane];
        float w02 = Wkm[(kk + 2) * 128 + lane];
        float w03 = Wkm[(kk + 3) * 128 + lane];
        float w10 = Wkm[(kk + 0) * 128 + lane + 64];
        float w11 = Wkm[(kk + 1) * 128 + lane + 64];
        float w12 = Wkm[(kk + 2) * 128 + lane + 64];
        float w13 = Wkm[(kk + 3) * 128 + lane + 64];
        #pragma unroll
        for (int p = 0; p < 4; ++p) {
            float4 a = *(const float4*)&a_lds[(pg * 4 + p) * KDIM + kk];  // broadcast
            acc[0][p] += a.x * w00 + a.y * w01 + a.z * w02 + a.w * w03;
            acc[1][p] += a.x * w10 + a.y * w11 + a.z * w12 + a.w * w13;
        }
    }
    __syncthreads();   // all a_lds reads done before aliasing overwrite

    // epilogue: stage via LDS, then coalesced global stores (proven path)
    float* outst = a_lds;                    // [128 co][17]
    #pragma unroll
    for (int c = 0; c < 2; ++c)
        #pragma unroll
        for (int p = 0; p < 4; ++p)
            outst[(lane + c * 64) * 17 + pg * 4 + p] = acc[c][p];
    __syncthreads();
    for (int e = tid; e < 2048; e += 256) {
        int co = e >> 4, wl = e & 15;
        out[((size_t)(b * 128 + co) * 16384) + h * 128 + w0 + wl] = outst[co * 17 + wl];
    }
}

// ---------------- BN stats: one block per (b, co) ----------------
__global__ __launch_bounds__(256) void k_stats(
    const float* __restrict__ out, float* __restrict__ partial) {
    __shared__ float s1[256], s2[256];
    int blk = blockIdx.x;
    const float4* p = (const float4*)(out + (size_t)blk * 16384);
    float a1 = 0.f, a2 = 0.f;
    for (int i = threadIdx.x; i < 4096; i += 256) {
        float4 v = p[i];
        a1 += v.x + v.y + v.z + v.w;
        a2 += v.x * v.x + v.y * v.y + v.z * v.z + v.w * v.w;
    }
    s1[threadIdx.x] = a1; s2[threadIdx.x] = a2;
    __syncthreads();
    for (int s = 128; s > 0; s >>= 1) {
        if (threadIdx.x < (unsigned)s) {
            s1[threadIdx.x] += s1[threadIdx.x + s];
            s2[threadIdx.x] += s2[threadIdx.x + s];
        }
        __syncthreads();
    }
    if (threadIdx.x == 0) { partial[blk] = s1[0]; partial[1024 + blk] = s2[0]; }
}

__global__ void k_finalize(const float* __restrict__ partial, const float* __restrict__ gamma,
                           const float* __restrict__ beta, float* __restrict__ sb) {
    int c = threadIdx.x;
    if (c < 128) {
        float s1 = 0.f, s2 = 0.f;
        for (int b = 0; b < 8; ++b) {
            s1 += partial[b * 128 + c];
            s2 += partial[1024 + b * 128 + c];
        }
        const float M = 131072.f;
        float mean = s1 / M;
        float var = fmaxf(s2 / M - mean * mean, 0.f);
        float sc = gamma[c] * rsqrtf(var + 1e-5f);
        sb[c] = sc;
        sb[128 + c] = beta[c] - mean * sc;
    }
}

__global__ void k_bnrelu(float* __restrict__ out, const float* __restrict__ sb) {
    int i = blockIdx.x * 256 + threadIdx.x;
    int c = (i >> 12) & 127;
    float4 v = ((float4*)out)[i];
    float sc = sb[c], bi = sb[128 + c];
    v.x = fmaxf(v.x * sc + bi, 0.f);
    v.y = fmaxf(v.y * sc + bi, 0.f);
    v.z = fmaxf(v.z * sc + bi, 0.f);
    v.w = fmaxf(v.w * sc + bi, 0.f);
    ((float4*)out)[i] = v;
}

extern "C" void kernel_launch(void* const* d_in, const int* in_sizes, int n_in,
                              void* d_out, int out_size, void* d_ws, size_t ws_size,
                              hipStream_t stream) {
    const float* x     = (const float*)d_in[0];
    const float* Wp    = (const float*)d_in[1];
    const float* bp    = (const float*)d_in[2];
    const float* Wm    = (const float*)d_in[3];
    const float* bm    = (const float*)d_in[4];
    const float* Wc    = (const float*)d_in[5];
    const float* gamma = (const float*)d_in[6];
    const float* beta  = (const float*)d_in[7];
    float* out = (float*)d_out;
    float* ws  = (float*)d_ws;

    // ws layout (floats)
    float* x_t     = ws;                         // 8,652,800
    float* Wkm     = x_t + 8652800;              // 73,728 (576*128 fp32, k-major)
    float* offs    = Wkm + 73728;                // 2,359,296
    float* mask    = offs + 2359296;             // 1,179,648
    float* partial = mask + 1179648;             // 2048
    float* sb      = partial + 2048;             // 256

    k_zero<<<8450, 256, 0, stream>>>((float4*)x_t, 2163200);
    k_pad_transpose<<<1024, 256, 0, stream>>>(x, x_t);
    k_wct<<<288, 256, 0, stream>>>(Wc, Wkm);
    k_offmask<<<2048, 256, 0, stream>>>(x_t, Wp, bp, Wm, bm, offs, mask);
    k_main<<<8192, 256, 0, stream>>>(x_t, offs, mask, Wkm, out);
    k_stats<<<1024, 256, 0, stream>>>(out, partial);
    k_finalize<<<1, 128, 0, stream>>>(partial, gamma, beta, sb);
    k_bnrelu<<<16384, 256, 0, stream>>>(out, sb);
}

// Round 12
// 704.422 us; speedup vs baseline: 1.9014x; 1.0092x over previous
//
#include <hip/hip_runtime.h>
#include <math.h>

// Problem constants: B=8, Cin=64, Cout=128, H=W=128, KS=3, N=9, K=576
#define KDIM 576

// ---------------- zero-fill x_t (border padding) ----------------
__global__ void k_zero(float4* __restrict__ p, int n4) {
    int i = blockIdx.x * 256 + threadIdx.x;
    if (i < n4) p[i] = make_float4(0.f, 0.f, 0.f, 0.f);
}

// ---------------- pad + NCHW->NHWC transpose ----------------
__global__ __launch_bounds__(256) void k_pad_transpose(
    const float* __restrict__ x, float* __restrict__ x_t) {
    __shared__ float lds[128 * 65];
    int b = blockIdx.x >> 7;
    int h = blockIdx.x & 127;
    for (int e = threadIdx.x; e < 64 * 128; e += 256) {
        int ci = e >> 7, w = e & 127;
        lds[w * 65 + ci] = x[((b * 64 + ci) * 128 + h) * 128 + w];
    }
    __syncthreads();
    for (int e = threadIdx.x; e < 128 * 64; e += 256) {
        int w = e >> 6, ci = e & 63;
        x_t[((b * 130 + h + 1) * 130 + (w + 1)) * 64 + ci] = lds[w * 65 + ci];
    }
}

// ---------------- W_conv -> fp32 k-major, K permuted: Wkm[k'][co], k' = n*64+ci ----------------
__global__ void k_wct(const float* __restrict__ Wc, float* __restrict__ Wkm) {
    int e = blockIdx.x * 256 + threadIdx.x;
    if (e >= 128 * KDIM) return;
    int co = e & 127, kp = e >> 7;
    int n = kp >> 6, ci = kp & 63;
    Wkm[e] = Wc[co * KDIM + ci * 9 + n];
}

// ---------------- offset + mask 3x3 convs (fp32, proven) ----------------
__global__ __launch_bounds__(256) void k_offmask(
    const float* __restrict__ x_t, const float* __restrict__ Wp, const float* __restrict__ bp,
    const float* __restrict__ Wm, const float* __restrict__ bm,
    float* __restrict__ offs, float* __restrict__ mask) {
    __shared__ float lds[198 * 65];
    int t = blockIdx.x;
    int wt = t & 1, h = (t >> 1) & 127, b = t >> 8;
    int w0 = wt * 64;
    for (int e = threadIdx.x; e < 198 * 64; e += 256) {
        int chunk = e >> 6, ci = e & 63;
        int row = chunk / 66, col = chunk % 66;
        lds[chunk * 65 + ci] = x_t[((b * 130 + h + row) * 130 + (w0 + col)) * 64 + ci];
    }
    __syncthreads();
    for (int e = threadIdx.x; e < 27 * 64; e += 256) {
        int oc = e >> 6, wl = e & 63;
        const float* wrow = (oc < 18) ? (Wp + oc * KDIM) : (Wm + (oc - 18) * KDIM);
        float acc = 0.f;
        for (int ci = 0; ci < 64; ++ci) {
            #pragma unroll
            for (int kx = 0; kx < 3; ++kx) {
                float x0 = lds[(kx * 66 + wl + 0) * 65 + ci];
                float x1 = lds[(kx * 66 + wl + 1) * 65 + ci];
                float x2 = lds[(kx * 66 + wl + 2) * 65 + ci];
                const float* wk = wrow + ci * 9 + kx * 3;
                acc += x0 * wk[0] + x1 * wk[1] + x2 * wk[2];
            }
        }
        int idx = ((b * 128 + h) * 128 + (w0 + wl));
        if (oc < 18) {
            offs[idx * 18 + oc] = acc + bp[oc];
        } else {
            float v = acc + bm[oc - 18];
            mask[idx * 9 + (oc - 18)] = 1.f / (1.f + __expf(-v));
        }
    }
}

// ---------------- main: deformable sample -> pipelined register-blocked VALU dot ----------------
// block = 16 positions; grid = 8192, XCD-pinned. LDS trimmed to 40896 B -> 4 blocks/CU.
// Phase 3: R11 topology (lane=co coalesced k-major weights, broadcast LDS A) +
// explicit 2-stage weight prefetch so loads overlap FMAs.
__global__ __launch_bounds__(256, 4) void k_main(
    const float* __restrict__ x_t, const float* __restrict__ offs,
    const float* __restrict__ mask, const float* __restrict__ Wkm,
    float* __restrict__ out) {
    __shared__ __align__(16) float a_lds[16 * KDIM];   // 36864 B; reused as outst
    __shared__ int    pi3[144 * 3];                    // lt, rb, dy (lb=lt+dy, rt=rb-dy)
    __shared__ float4 pg4[144];

    int blk = blockIdx.x;
    int b  = blk & 7;                  // XCD swizzle: one batch per XCD
    int rem = blk >> 3;
    int h  = rem >> 3;
    int w0 = (rem & 7) * 16;
    int tid = threadIdx.x;

    // phase 1: sampling coords for 16 pos x 9 pts (proven math, packed pi)
    if (tid < 144) {
        int e = tid;
        int pos = e / 9, n = e - pos * 9;
        int w = w0 + pos;
        int idx = ((b * 128 + h) * 128 + w);
        float ox = offs[idx * 18 + n];
        float oy = offs[idx * 18 + 9 + n];
        float mv = mask[idx * 9 + n];
        float px = ox + (float)(h + n / 3);
        float py = oy + (float)(w + n % 3);
        float flx = floorf(px), fly = floorf(py);
        float qltx = fminf(fmaxf(flx, 0.f), 129.f);
        float qlty = fminf(fmaxf(fly, 0.f), 129.f);
        float qrbx = fminf(fmaxf(flx + 1.f, 0.f), 129.f);
        float qrby = fminf(fmaxf(fly + 1.f, 0.f), 129.f);
        float pxc = fminf(fmaxf(px, 0.f), 129.f);
        float pyc = fminf(fmaxf(py, 0.f), 129.f);
        float glt = (1.f + qltx - pxc) * (1.f + qlty - pyc);
        float grb = (1.f - qrbx + pxc) * (1.f - qrby + pyc);
        float glb = (1.f + qltx - pxc) * (1.f - qrby + pyc);
        float grt = (1.f - qrbx + pxc) * (1.f + qlty - pyc);
        int ix_lt = (int)qltx, iy_lt = (int)qlty, ix_rb = (int)qrbx, iy_rb = (int)qrby;
        int lt = (ix_lt * 130 + iy_lt) * 64;
        int rb = (ix_rb * 130 + iy_rb) * 64;
        int dy = (iy_rb - iy_lt) * 64;
        pi3[e * 3 + 0] = lt;
        pi3[e * 3 + 1] = rb;
        pi3[e * 3 + 2] = dy;
        pg4[e] = make_float4(glt * mv, grb * mv, glb * mv, grt * mv);
    }
    __syncthreads();

    // phase 2: gather+blend, a_lds[pos][k' = n*64 + ci] in fp32 (proven pattern)
    {
        const float* xb = x_t + (size_t)b * 130 * 130 * 64;
        int ci = tid & 63;
        for (int it = 0; it < 36; ++it) {
            int point = (tid >> 6) + it * 4;
            int pos = (point * 456) >> 12;          // point/9, exact for point<288
            int n = point - pos * 9;
            int lt = pi3[point * 3 + 0];
            int rb = pi3[point * 3 + 1];
            int dy = pi3[point * 3 + 2];
            float4 g = pg4[point];
            float v = g.x * xb[lt + ci] + g.y * xb[rb + ci] +
                      g.z * xb[lt + dy + ci] + g.w * xb[rb - dy + ci];
            a_lds[pos * KDIM + n * 64 + ci] = v;
        }
    }
    __syncthreads();

    // phase 3: pipelined dot. lane = co (coalesced weights), pg = pos-group.
    int lane = tid & 63, pg = tid >> 6;
    const float* W0 = Wkm + lane;
    float acc[2][4] = {{0.f, 0.f, 0.f, 0.f}, {0.f, 0.f, 0.f, 0.f}};
    // prefetch weights for k4 = 0
    float c0 = W0[0],  c1 = W0[128], c2 = W0[256], c3 = W0[384];
    float c4 = W0[64], c5 = W0[192], c6 = W0[320], c7 = W0[448];
    #pragma unroll 2
    for (int k4 = 0; k4 < 144; ++k4) {
        // prefetch next iteration's weights (last iter over-reads 2KB into offs: benign)
        const float* Wn = W0 + (k4 + 1) * 512;
        float n0 = Wn[0],  n1 = Wn[128], n2 = Wn[256], n3 = Wn[384];
        float n4 = Wn[64], n5 = Wn[192], n6 = Wn[320], n7 = Wn[448];
        int kk = k4 * 4;
        float4 a0 = *(const float4*)&a_lds[(pg * 4 + 0) * KDIM + kk];
        float4 a1 = *(const float4*)&a_lds[(pg * 4 + 1) * KDIM + kk];
        float4 a2 = *(const float4*)&a_lds[(pg * 4 + 2) * KDIM + kk];
        float4 a3 = *(const float4*)&a_lds[(pg * 4 + 3) * KDIM + kk];
        acc[0][0] += a0.x * c0 + a0.y * c1 + a0.z * c2 + a0.w * c3;
        acc[1][0] += a0.x * c4 + a0.y * c5 + a0.z * c6 + a0.w * c7;
        acc[0][1] += a1.x * c0 + a1.y * c1 + a1.z * c2 + a1.w * c3;
        acc[1][1] += a1.x * c4 + a1.y * c5 + a1.z * c6 + a1.w * c7;
        acc[0][2] += a2.x * c0 + a2.y * c1 + a2.z * c2 + a2.w * c3;
        acc[1][2] += a2.x * c4 + a2.y * c5 + a2.z * c6 + a2.w * c7;
        acc[0][3] += a3.x * c0 + a3.y * c1 + a3.z * c2 + a3.w * c3;
        acc[1][3] += a3.x * c4 + a3.y * c5 + a3.z * c6 + a3.w * c7;
        c0 = n0; c1 = n1; c2 = n2; c3 = n3;
        c4 = n4; c5 = n5; c6 = n6; c7 = n7;
    }
    __syncthreads();   // all a_lds reads done before aliasing overwrite

    // epilogue: stage via LDS, then coalesced global stores (proven path)
    float* outst = a_lds;                    // [128 co][17]
    #pragma unroll
    for (int c = 0; c < 2; ++c)
        #pragma unroll
        for (int p = 0; p < 4; ++p)
            outst[(lane + c * 64) * 17 + pg * 4 + p] = acc[c][p];
    __syncthreads();
    for (int e = tid; e < 2048; e += 256) {
        int co = e >> 4, wl = e & 15;
        out[((size_t)(b * 128 + co) * 16384) + h * 128 + w0 + wl] = outst[co * 17 + wl];
    }
}

// ---------------- BN stats: one block per (b, co) ----------------
__global__ __launch_bounds__(256) void k_stats(
    const float* __restrict__ out, float* __restrict__ partial) {
    __shared__ float s1[256], s2[256];
    int blk = blockIdx.x;
    const float4* p = (const float4*)(out + (size_t)blk * 16384);
    float a1 = 0.f, a2 = 0.f;
    for (int i = threadIdx.x; i < 4096; i += 256) {
        float4 v = p[i];
        a1 += v.x + v.y + v.z + v.w;
        a2 += v.x * v.x + v.y * v.y + v.z * v.z + v.w * v.w;
    }
    s1[threadIdx.x] = a1; s2[threadIdx.x] = a2;
    __syncthreads();
    for (int s = 128; s > 0; s >>= 1) {
        if (threadIdx.x < (unsigned)s) {
            s1[threadIdx.x] += s1[threadIdx.x + s];
            s2[threadIdx.x] += s2[threadIdx.x + s];
        }
        __syncthreads();
    }
    if (threadIdx.x == 0) { partial[blk] = s1[0]; partial[1024 + blk] = s2[0]; }
}

__global__ void k_finalize(const float* __restrict__ partial, const float* __restrict__ gamma,
                           const float* __restrict__ beta, float* __restrict__ sb) {
    int c = threadIdx.x;
    if (c < 128) {
        float s1 = 0.f, s2 = 0.f;
        for (int b = 0; b < 8; ++b) {
            s1 += partial[b * 128 + c];
            s2 += partial[1024 + b * 128 + c];
        }
        const float M = 131072.f;
        float mean = s1 / M;
        float var = fmaxf(s2 / M - mean * mean, 0.f);
        float sc = gamma[c] * rsqrtf(var + 1e-5f);
        sb[c] = sc;
        sb[128 + c] = beta[c] - mean * sc;
    }
}

__global__ void k_bnrelu(float* __restrict__ out, const float* __restrict__ sb) {
    int i = blockIdx.x * 256 + threadIdx.x;
    int c = (i >> 12) & 127;
    float4 v = ((float4*)out)[i];
    float sc = sb[c], bi = sb[128 + c];
    v.x = fmaxf(v.x * sc + bi, 0.f);
    v.y = fmaxf(v.y * sc + bi, 0.f);
    v.z = fmaxf(v.z * sc + bi, 0.f);
    v.w = fmaxf(v.w * sc + bi, 0.f);
    ((float4*)out)[i] = v;
}

extern "C" void kernel_launch(void* const* d_in, const int* in_sizes, int n_in,
                              void* d_out, int out_size, void* d_ws, size_t ws_size,
                              hipStream_t stream) {
    const float* x     = (const float*)d_in[0];
    const float* Wp    = (const float*)d_in[1];
    const float* bp    = (const float*)d_in[2];
    const float* Wm    = (const float*)d_in[3];
    const float* bm    = (const float*)d_in[4];
    const float* Wc    = (const float*)d_in[5];
    const float* gamma = (const float*)d_in[6];
    const float* beta  = (const float*)d_in[7];
    float* out = (float*)d_out;
    float* ws  = (float*)d_ws;

    // ws layout (floats)
    float* x_t     = ws;                         // 8,652,800
    float* Wkm     = x_t + 8652800;              // 73,728 (576*128 fp32, k-major)
    float* offs    = Wkm + 73728;                // 2,359,296 (also absorbs the benign over-read)
    float* mask    = offs + 2359296;             // 1,179,648
    float* partial = mask + 1179648;             // 2048
    float* sb      = partial + 2048;             // 256

    k_zero<<<8450, 256, 0, stream>>>((float4*)x_t, 2163200);
    k_pad_transpose<<<1024, 256, 0, stream>>>(x, x_t);
    k_wct<<<288, 256, 0, stream>>>(Wc, Wkm);
    k_offmask<<<2048, 256, 0, stream>>>(x_t, Wp, bp, Wm, bm, offs, mask);
    k_main<<<8192, 256, 0, stream>>>(x_t, offs, mask, Wkm, out);
    k_stats<<<1024, 256, 0, stream>>>(out, partial);
    k_finalize<<<1, 128, 0, stream>>>(partial, gamma, beta, sb);
    k_bnrelu<<<16384, 256, 0, stream>>>(out, sb);
}